// Round 2
// baseline (165.041 us; speedup 1.0000x reference)
//
#include <hip/hip_runtime.h>
#include <hip/hip_cooperative_groups.h>

namespace cg = cooperative_groups;

#define Bn 4096
#define Dn 66
#define Hn 512

typedef __attribute__((ext_vector_type(8))) short short8;
typedef __attribute__((ext_vector_type(4))) float f32x4;

__device__ __forceinline__ unsigned short f2bf(float x) {
    union { float f; unsigned u; } v; v.f = x;
    unsigned r = v.u + 0x7fffu + ((v.u >> 16) & 1u);   // RNE
    return (unsigned short)(r >> 16);
}
__device__ __forceinline__ float bf2f(unsigned short h) {
    union { float f; unsigned u; } v; v.u = ((unsigned)h) << 16; return v.f;
}

// Layouts (unchanged from previous verified kernels):
//   A-frag tile ks: lane l holds A[l&15][ks*32 + (l>>4)*8 + j]  at (ks*64 + l)*8 + j
//   WQ interleaved B-frag tile (ct, ks): W2-frag at ((ct*16+ks)*64+l)*16 + 0..7,
//       Cm-frag at +8..15
//   W3P B-frag tile (jt, ks): ((jt*16+ks)*64 + l)*8 + j

// ============ k_all: ONE cooperative dispatch, grid 256 x 1024 ============
// Per block rt (owning batch rows [rt*16, rt*16+16)):
//   1. stage x~^T into LDS
//   2. pack tasks (waves 0..2 only): WQ tile wv*256+rt, W3P tile rt (rt<80)
//      -> weight-only, written to global workspace
//   3. phase A: z1 = [x,t]@W1 + b1 (fp32 VALU), h1hi/s1 frags -> LDS
//   4. grid.sync()  (replaces the old kernel boundary: WQ/W3P now visible)
//   5. phase B: z2 = h1hi@W2 + b2, v = s1'@Cm   (MFMA, WQ depth-1 prefetch)
//   6. epilogue: h2 hi/lo -> LDS, divergence reduce
//   7. phase C: out = h2@W3 + b3 (waves 0..4)
__global__ __launch_bounds__(1024, 4) void k_all(
    const float* __restrict__ xs, const float* __restrict__ tt,
    const float* __restrict__ W1, const float* __restrict__ b1,
    const float* __restrict__ W2, const float* __restrict__ b2,
    const float* __restrict__ W3, const float* __restrict__ b3,
    unsigned short* __restrict__ WQ, unsigned short* __restrict__ W3P,
    float* __restrict__ out)
{
    __shared__ float sX[67*16];                          // x~^T staging [i][r]
    __shared__ __align__(16) unsigned short sA[8192];    // h1 hi A-frags (16 KB)
    __shared__ __align__(16) unsigned short sS[8192];    // s1 A-frags   (16 KB)
    __shared__ __align__(16) unsigned short sH[8192];    // h2 hi (16 KB)
    __shared__ __align__(16) unsigned short sL[8192];    // h2 lo (16 KB)
    __shared__ float sRed[16*16];

    const int tid = threadIdx.x, lane = tid & 63, wv = tid >> 6;   // wv 0..15
    const int rt = blockIdx.x, r0 = rt*16;
    const int n = lane & 15, kg = lane >> 4;
    const int rot = (rt >> 3) & 15;

    // ---- stage x~^T (row 66 = t) into sX[i*16 + r] ----
    for (int idx = tid; idx < 67*16; idx += 1024) {
        const int i = idx >> 4, r = idx & 15;
        sX[idx] = (i < Dn) ? xs[(size_t)(r0+r)*Dn + i] : tt[r0+r];
    }
    __syncthreads();

    // ---- pack tasks (weight-only): waves 0,1 -> WQ tile; wave 2 -> W3P tile ----
    if (wv < 2) {
        const int tix = wv*256 + rt;               // 0..511 = (ct 0..31, ks 0..15)
        const int ct = tix >> 4, ks = tix & 15;
        const int c = ct*16 + n;
        const int abase = ks*32 + kg*8;
        float w2v[8], m[8];
        #pragma unroll
        for (int j = 0; j < 8; ++j) {
            w2v[j] = W2[(size_t)(abase + j)*Hn + c];
            m[j] = 0.f;
        }
        const float* w3row = &W3[(size_t)c * Dn];
        #pragma unroll 2
        for (int i = 0; i < Dn; ++i) {
            const float w3 = w3row[i];
            const float4 w1a = *(const float4*)&W1[(size_t)i*Hn + abase];
            const float4 w1b = *(const float4*)&W1[(size_t)i*Hn + abase + 4];
            m[0] = fmaf(w3, w1a.x, m[0]); m[1] = fmaf(w3, w1a.y, m[1]);
            m[2] = fmaf(w3, w1a.z, m[2]); m[3] = fmaf(w3, w1a.w, m[3]);
            m[4] = fmaf(w3, w1b.x, m[4]); m[5] = fmaf(w3, w1b.y, m[5]);
            m[6] = fmaf(w3, w1b.z, m[6]); m[7] = fmaf(w3, w1b.w, m[7]);
        }
        short8 pw, pc;
        #pragma unroll
        for (int j = 0; j < 8; ++j) {
            pw[j] = (short)f2bf(w2v[j]);
            pc[j] = (short)f2bf(w2v[j] * m[j]);
        }
        const size_t off = ((size_t)tix*64 + lane)*16;
        *(short8*)&WQ[off]     = pw;
        *(short8*)&WQ[off + 8] = pc;
    } else if (wv == 2 && rt < 80) {
        const int tix = rt;                        // 0..79 = (jt 0..4, ks 0..15)
        const int ks = tix & 15;
        const int j_out = (tix >> 4)*16 + n;
        const int abase = ks*32 + kg*8;
        short8 p;
        #pragma unroll
        for (int j = 0; j < 8; ++j)
            p[j] = (j_out < Dn) ? (short)f2bf(W3[(size_t)(abase + j)*Dn + j_out]) : (short)0;
        *(short8*)&W3P[((size_t)tix*64 + lane)*8] = p;
    }

    // ---- phase A: z1 = [x,t]@W1 + b1 (fp32 VALU); wave wv owns ks-tile wv ----
    {
        const int rg = lane & 7, cg = lane >> 3;
        const int ks = wv;
        const int c0 = ks*32 + cg*4;
        const int irot = (rt >> 3) & 31;
        float z[2][4];
        {
            const float4 b4 = *(const float4*)&b1[c0];
            z[0][0]=b4.x; z[0][1]=b4.y; z[0][2]=b4.z; z[0][3]=b4.w;
            z[1][0]=b4.x; z[1][1]=b4.y; z[1][2]=b4.z; z[1][3]=b4.w;
        }
        #pragma unroll 2
        for (int s = 0; s < 67; ++s) {
            int i = s + irot; if (i >= 67) i -= 67;
            const float2 xf = *(const float2*)&sX[i*16 + 2*rg];
            const float4 wA = *(const float4*)&W1[(size_t)i*Hn + c0];
            const float ww[4] = {wA.x, wA.y, wA.z, wA.w};
            #pragma unroll
            for (int j = 0; j < 4; ++j) {
                z[0][j] = fmaf(xf.x, ww[j], z[0][j]);
                z[1][j] = fmaf(xf.y, ww[j], z[1][j]);
            }
        }
        const int kgrp = cg >> 1, joff = (cg & 1)*4;
        #pragma unroll
        for (int rr = 0; rr < 2; ++rr) {
            const int r = 2*rg + rr;
            ushort4 phi, ps;
            unsigned short* PH = (unsigned short*)&phi;
            unsigned short* PS = (unsigned short*)&ps;
            #pragma unroll
            for (int j = 0; j < 4; ++j) {
                const float zv = z[rr][j];
                const float sg = 1.f / (1.f + __expf(-zv));
                PH[j] = f2bf(zv * sg);
                PS[j] = f2bf(sg * (1.f + zv * (1.f - sg)));
            }
            const int off = (ks*64 + r + 16*kgrp)*8 + joff;
            *(ushort4*)&sA[off] = phi;
            *(ushort4*)&sS[off] = ps;
        }
    }

    // ---- grid-wide barrier: WQ/W3P stores + LDS A-frags all visible after ----
    cg::this_grid().sync();

    // ---- phase B: z2 = h1hi@W2 + b2, v = s1'@Cmat; A/S from LDS, WQ prefetched ----
    const int ctb = wv*2;
    f32x4 zac[2], vac[2];
    #pragma unroll
    for (int ti = 0; ti < 2; ++ti) {
        const float bz = b2[(ctb + ti)*16 + n];
        zac[ti] = (f32x4){bz, bz, bz, bz};
        vac[ti] = (f32x4){0.f, 0.f, 0.f, 0.f};
    }
    short8 wbuf[2][2], qbuf[2][2], abuf[2], sbuf[2];
    {
        const int ks0 = rot;
        abuf[0] = *(const short8*)&sA[(ks0*64 + lane)*8];
        sbuf[0] = *(const short8*)&sS[(ks0*64 + lane)*8];
        #pragma unroll
        for (int ti = 0; ti < 2; ++ti) {
            const size_t wo = ((size_t)((ctb + ti)*16 + ks0)*64 + lane)*16;
            wbuf[0][ti] = *(const short8*)&WQ[wo];
            qbuf[0][ti] = *(const short8*)&WQ[wo + 8];
        }
    }
    #pragma unroll
    for (int s = 0; s < 16; ++s) {
        const int cur = s & 1, nxt = cur ^ 1;
        if (s < 15) {
            const int ksn = (s + 1 + rot) & 15;
            abuf[nxt] = *(const short8*)&sA[(ksn*64 + lane)*8];
            sbuf[nxt] = *(const short8*)&sS[(ksn*64 + lane)*8];
            #pragma unroll
            for (int ti = 0; ti < 2; ++ti) {
                const size_t wo = ((size_t)((ctb + ti)*16 + ksn)*64 + lane)*16;
                wbuf[nxt][ti] = *(const short8*)&WQ[wo];
                qbuf[nxt][ti] = *(const short8*)&WQ[wo + 8];
            }
        }
        #pragma unroll
        for (int ti = 0; ti < 2; ++ti) {
            zac[ti] = __builtin_amdgcn_mfma_f32_16x16x32_bf16(abuf[cur], wbuf[cur][ti], zac[ti], 0, 0, 0);
            vac[ti] = __builtin_amdgcn_mfma_f32_16x16x32_bf16(sbuf[cur], qbuf[cur][ti], vac[ti], 0, 0, 0);
        }
    }

    // ---- epilogue: h2 hi/lo -> LDS; dp partial reduce ----
    float dp[4] = {0.f, 0.f, 0.f, 0.f};
    #pragma unroll
    for (int ti = 0; ti < 2; ++ti) {
        const int c = (ctb + ti)*16 + n;
        const int ks2 = c >> 5, kg2 = (c >> 3) & 3, j2 = c & 7;
        #pragma unroll
        for (int q = 0; q < 4; ++q) {
            const float z2 = zac[ti][q];
            const float sg = 1.f / (1.f + __expf(-z2));
            const float h2 = z2 * sg;
            dp[q] = fmaf(sg * (1.f + z2 * (1.f - sg)), vac[ti][q], dp[q]);
            const unsigned short hh = f2bf(h2);
            const int o = (ks2*64 + (kg*4 + q) + 16*kg2)*8 + j2;
            sH[o] = hh;
            sL[o] = f2bf(h2 - bf2f(hh));
        }
    }
    #pragma unroll
    for (int q = 0; q < 4; ++q) {
        float v = dp[q];
        v += __shfl_xor(v, 1, 64);
        v += __shfl_xor(v, 2, 64);
        v += __shfl_xor(v, 4, 64);
        v += __shfl_xor(v, 8, 64);
        if (n == 0) sRed[wv*16 + kg*4 + q] = v;
    }
    __syncthreads();

    // ---- divergence finalize ----
    if (tid < 16) {
        float s = 0.f;
        #pragma unroll
        for (int q = 0; q < 16; ++q) s += sRed[q*16 + tid];
        out[(size_t)Bn*Dn + r0 + tid] = -s;
    }

    // ---- phase C: out = h2 @ W3 + b3 (waves 0..4); rotated ks ----
    if (wv < 5) {
        const int jt = wv;
        const int j = jt*16 + n;
        const float bj = (j < Dn) ? b3[j] : 0.f;
        f32x4 oac = (f32x4){bj, bj, bj, bj};
        #pragma unroll 4
        for (int s = 0; s < 16; ++s) {
            const int ks = (s + rot) & 15;
            const int aoff = (ks*64 + lane)*8;
            const short8 ahi = *(const short8*)&sH[aoff];
            const short8 alo = *(const short8*)&sL[aoff];
            const short8 wf  = *(const short8*)&W3P[((size_t)(jt*16 + ks)*64 + lane)*8];
            oac = __builtin_amdgcn_mfma_f32_16x16x32_bf16(ahi, wf, oac, 0, 0, 0);
            oac = __builtin_amdgcn_mfma_f32_16x16x32_bf16(alo, wf, oac, 0, 0, 0);
        }
        if (j < Dn) {
            #pragma unroll
            for (int q = 0; q < 4; ++q)
                out[(size_t)(r0 + kg*4 + q)*Dn + j] = oac[q];
        }
    }
}

extern "C" void kernel_launch(void* const* d_in, const int* in_sizes, int n_in,
                              void* d_out, int out_size, void* d_ws, size_t ws_size,
                              hipStream_t stream)
{
    const float* xs = (const float*)d_in[0];
    const float* t  = (const float*)d_in[1];
    const float* W1 = (const float*)d_in[2];
    const float* b1 = (const float*)d_in[3];
    const float* W2 = (const float*)d_in[4];
    const float* b2 = (const float*)d_in[5];
    const float* W3 = (const float*)d_in[6];
    const float* b3 = (const float*)d_in[7];
    float* out = (float*)d_out;

    char* ws = (char*)d_ws;
    unsigned short* WQ  = (unsigned short*)(ws);             // 1 MB interleaved W2|Cm
    unsigned short* W3P = (unsigned short*)(ws + 1048576);   // 80 KB

    void* args[] = {&xs, &t, &W1, &b1, &W2, &b2, &W3, &b3, &WQ, &W3P, &out};
    hipLaunchCooperativeKernel((const void*)k_all, dim3(256), dim3(1024),
                               args, 0, stream);
}

// Round 3
// 135.846 us; speedup vs baseline: 1.2149x; 1.2149x over previous
//
#include <hip/hip_runtime.h>

#define Bn 4096
#define Dn 66
#define Hn 512

typedef __attribute__((ext_vector_type(8))) short short8;
typedef __attribute__((ext_vector_type(4))) float f32x4;

__device__ __forceinline__ unsigned short f2bf(float x) {
    union { float f; unsigned u; } v; v.f = x;
    unsigned r = v.u + 0x7fffu + ((v.u >> 16) & 1u);   // RNE
    return (unsigned short)(r >> 16);
}
__device__ __forceinline__ float bf2f(unsigned short h) {
    union { float f; unsigned u; } v; v.u = ((unsigned)h) << 16; return v.f;
}

// Layouts (unchanged from verified kernels):
//   A-frag tile ks: lane l holds A[l&15][ks*32 + (l>>4)*8 + j]  at (ks*64 + l)*8 + j
//   WQ interleaved B-frag tile (ct, ks): W2-frag at ((ct*16+ks)*64+l)*16 + 0..7,
//       Cm-frag at +8..15
//   W3P B-frag tile (jt, ks): ((jt*16+ks)*64 + l)*8 + j

// ============ k_single: ONE regular dispatch, grid 256 x 1024 ============
// Producer side (per block rt): waves 0,1 pack WQ tiles wv*256+rt; wave 2 packs
// W3P tile rt (rt<80). After pack + phase A, block release-adds doneCtr.
// Consumer side: acquire-spin until doneCtr==256 (s_sleep backoff), then B/C.
// Deadlock-free: grid(256) <= CU count(256) at 71KB LDS -> all blocks resident
// before any spin; spin waits only on running blocks' bounded work.
__global__ __launch_bounds__(1024, 4) void k_single(
    const float* __restrict__ xs, const float* __restrict__ tt,
    const float* __restrict__ W1, const float* __restrict__ b1,
    const float* __restrict__ W2, const float* __restrict__ b2,
    const float* __restrict__ W3, const float* __restrict__ b3,
    unsigned short* __restrict__ WQ, unsigned short* __restrict__ W3P,
    unsigned int* __restrict__ doneCtr,
    float* __restrict__ out)
{
    __shared__ float sX[67*16];                          // x~^T staging [i][r]
    __shared__ __align__(16) unsigned short sA[8192];    // h1 hi A-frags (16 KB)
    __shared__ __align__(16) unsigned short sS[8192];    // s1 A-frags   (16 KB)
    __shared__ __align__(16) unsigned short sH[8192];    // h2 hi (16 KB)
    __shared__ __align__(16) unsigned short sL[8192];    // h2 lo (16 KB)
    __shared__ float sRed[16*16];

    const int tid = threadIdx.x, lane = tid & 63, wv = tid >> 6;   // wv 0..15
    const int rt = blockIdx.x, r0 = rt*16;
    const int n = lane & 15, kg = lane >> 4;
    const int rot = (rt >> 3) & 15;

    // ---- stage x~^T (row 66 = t) into sX[i*16 + r] ----
    for (int idx = tid; idx < 67*16; idx += 1024) {
        const int i = idx >> 4, r = idx & 15;
        sX[idx] = (i < Dn) ? xs[(size_t)(r0+r)*Dn + i] : tt[r0+r];
    }
    __syncthreads();

    // ---- pack tasks (weight-only, verified round-2 code) ----
    if (wv < 2) {
        const int tix = wv*256 + rt;               // 0..511 = (ct 0..31, ks 0..15)
        const int ct = tix >> 4, ks = tix & 15;
        const int c = ct*16 + n;
        const int abase = ks*32 + kg*8;
        float w2v[8], m[8];
        #pragma unroll
        for (int j = 0; j < 8; ++j) {
            w2v[j] = W2[(size_t)(abase + j)*Hn + c];
            m[j] = 0.f;
        }
        const float* w3row = &W3[(size_t)c * Dn];
        #pragma unroll 2
        for (int i = 0; i < Dn; ++i) {
            const float w3 = w3row[i];
            const float4 w1a = *(const float4*)&W1[(size_t)i*Hn + abase];
            const float4 w1b = *(const float4*)&W1[(size_t)i*Hn + abase + 4];
            m[0] = fmaf(w3, w1a.x, m[0]); m[1] = fmaf(w3, w1a.y, m[1]);
            m[2] = fmaf(w3, w1a.z, m[2]); m[3] = fmaf(w3, w1a.w, m[3]);
            m[4] = fmaf(w3, w1b.x, m[4]); m[5] = fmaf(w3, w1b.y, m[5]);
            m[6] = fmaf(w3, w1b.z, m[6]); m[7] = fmaf(w3, w1b.w, m[7]);
        }
        short8 pw, pc;
        #pragma unroll
        for (int j = 0; j < 8; ++j) {
            pw[j] = (short)f2bf(w2v[j]);
            pc[j] = (short)f2bf(w2v[j] * m[j]);
        }
        const size_t off = ((size_t)tix*64 + lane)*16;
        *(short8*)&WQ[off]     = pw;
        *(short8*)&WQ[off + 8] = pc;
        __threadfence();                            // device-visible before signal
    } else if (wv == 2 && rt < 80) {
        const int tix = rt;                        // 0..79 = (jt 0..4, ks 0..15)
        const int ks = tix & 15;
        const int j_out = (tix >> 4)*16 + n;
        const int abase = ks*32 + kg*8;
        short8 p;
        #pragma unroll
        for (int j = 0; j < 8; ++j)
            p[j] = (j_out < Dn) ? (short)f2bf(W3[(size_t)(abase + j)*Dn + j_out]) : (short)0;
        *(short8*)&W3P[((size_t)tix*64 + lane)*8] = p;
        __threadfence();
    }

    // ---- phase A: z1 = [x,t]@W1 + b1 (fp32 VALU); wave wv owns ks-tile wv ----
    {
        const int rg = lane & 7, cg = lane >> 3;
        const int ks = wv;
        const int c0 = ks*32 + cg*4;
        const int irot = (rt >> 3) & 31;
        float z[2][4];
        {
            const float4 b4 = *(const float4*)&b1[c0];
            z[0][0]=b4.x; z[0][1]=b4.y; z[0][2]=b4.z; z[0][3]=b4.w;
            z[1][0]=b4.x; z[1][1]=b4.y; z[1][2]=b4.z; z[1][3]=b4.w;
        }
        #pragma unroll 2
        for (int s = 0; s < 67; ++s) {
            int i = s + irot; if (i >= 67) i -= 67;
            const float2 xf = *(const float2*)&sX[i*16 + 2*rg];
            const float4 wA = *(const float4*)&W1[(size_t)i*Hn + c0];
            const float ww[4] = {wA.x, wA.y, wA.z, wA.w};
            #pragma unroll
            for (int j = 0; j < 4; ++j) {
                z[0][j] = fmaf(xf.x, ww[j], z[0][j]);
                z[1][j] = fmaf(xf.y, ww[j], z[1][j]);
            }
        }
        const int kgrp = cg >> 1, joff = (cg & 1)*4;
        #pragma unroll
        for (int rr = 0; rr < 2; ++rr) {
            const int r = 2*rg + rr;
            ushort4 phi, ps;
            unsigned short* PH = (unsigned short*)&phi;
            unsigned short* PS = (unsigned short*)&ps;
            #pragma unroll
            for (int j = 0; j < 4; ++j) {
                const float zv = z[rr][j];
                const float sg = 1.f / (1.f + __expf(-zv));
                PH[j] = f2bf(zv * sg);
                PS[j] = f2bf(sg * (1.f + zv * (1.f - sg)));
            }
            const int off = (ks*64 + r + 16*kgrp)*8 + joff;
            *(ushort4*)&sA[off] = phi;
            *(ushort4*)&sS[off] = ps;
        }
    }

    // ---- signal: this block's pack is device-visible; LDS A-frags ready ----
    __syncthreads();
    if (tid == 0)
        __hip_atomic_fetch_add(doneCtr, 1u, __ATOMIC_RELEASE, __HIP_MEMORY_SCOPE_AGENT);

    // ---- wait: all 256 blocks' pack done (one lane spins, backoff) ----
    if (tid == 0) {
        while (__hip_atomic_load(doneCtr, __ATOMIC_ACQUIRE, __HIP_MEMORY_SCOPE_AGENT) < 256u)
            __builtin_amdgcn_s_sleep(32);
    }
    __syncthreads();

    // ---- phase B: z2 = h1hi@W2 + b2, v = s1'@Cmat; A/S from LDS, WQ prefetched ----
    const int ctb = wv*2;
    f32x4 zac[2], vac[2];
    #pragma unroll
    for (int ti = 0; ti < 2; ++ti) {
        const float bz = b2[(ctb + ti)*16 + n];
        zac[ti] = (f32x4){bz, bz, bz, bz};
        vac[ti] = (f32x4){0.f, 0.f, 0.f, 0.f};
    }
    short8 wbuf[2][2], qbuf[2][2], abuf[2], sbuf[2];
    {
        const int ks0 = rot;
        abuf[0] = *(const short8*)&sA[(ks0*64 + lane)*8];
        sbuf[0] = *(const short8*)&sS[(ks0*64 + lane)*8];
        #pragma unroll
        for (int ti = 0; ti < 2; ++ti) {
            const size_t wo = ((size_t)((ctb + ti)*16 + ks0)*64 + lane)*16;
            wbuf[0][ti] = *(const short8*)&WQ[wo];
            qbuf[0][ti] = *(const short8*)&WQ[wo + 8];
        }
    }
    #pragma unroll
    for (int s = 0; s < 16; ++s) {
        const int cur = s & 1, nxt = cur ^ 1;
        if (s < 15) {
            const int ksn = (s + 1 + rot) & 15;
            abuf[nxt] = *(const short8*)&sA[(ksn*64 + lane)*8];
            sbuf[nxt] = *(const short8*)&sS[(ksn*64 + lane)*8];
            #pragma unroll
            for (int ti = 0; ti < 2; ++ti) {
                const size_t wo = ((size_t)((ctb + ti)*16 + ksn)*64 + lane)*16;
                wbuf[nxt][ti] = *(const short8*)&WQ[wo];
                qbuf[nxt][ti] = *(const short8*)&WQ[wo + 8];
            }
        }
        #pragma unroll
        for (int ti = 0; ti < 2; ++ti) {
            zac[ti] = __builtin_amdgcn_mfma_f32_16x16x32_bf16(abuf[cur], wbuf[cur][ti], zac[ti], 0, 0, 0);
            vac[ti] = __builtin_amdgcn_mfma_f32_16x16x32_bf16(sbuf[cur], qbuf[cur][ti], vac[ti], 0, 0, 0);
        }
    }

    // ---- epilogue: h2 hi/lo -> LDS; dp partial reduce ----
    float dp[4] = {0.f, 0.f, 0.f, 0.f};
    #pragma unroll
    for (int ti = 0; ti < 2; ++ti) {
        const int c = (ctb + ti)*16 + n;
        const int ks2 = c >> 5, kg2 = (c >> 3) & 3, j2 = c & 7;
        #pragma unroll
        for (int q = 0; q < 4; ++q) {
            const float z2 = zac[ti][q];
            const float sg = 1.f / (1.f + __expf(-z2));
            const float h2 = z2 * sg;
            dp[q] = fmaf(sg * (1.f + z2 * (1.f - sg)), vac[ti][q], dp[q]);
            const unsigned short hh = f2bf(h2);
            const int o = (ks2*64 + (kg*4 + q) + 16*kg2)*8 + j2;
            sH[o] = hh;
            sL[o] = f2bf(h2 - bf2f(hh));
        }
    }
    #pragma unroll
    for (int q = 0; q < 4; ++q) {
        float v = dp[q];
        v += __shfl_xor(v, 1, 64);
        v += __shfl_xor(v, 2, 64);
        v += __shfl_xor(v, 4, 64);
        v += __shfl_xor(v, 8, 64);
        if (n == 0) sRed[wv*16 + kg*4 + q] = v;
    }
    __syncthreads();

    // ---- divergence finalize ----
    if (tid < 16) {
        float s = 0.f;
        #pragma unroll
        for (int q = 0; q < 16; ++q) s += sRed[q*16 + tid];
        out[(size_t)Bn*Dn + r0 + tid] = -s;
    }

    // ---- phase C: out = h2 @ W3 + b3 (waves 0..4); rotated ks ----
    if (wv < 5) {
        const int jt = wv;
        const int j = jt*16 + n;
        const float bj = (j < Dn) ? b3[j] : 0.f;
        f32x4 oac = (f32x4){bj, bj, bj, bj};
        #pragma unroll 4
        for (int s = 0; s < 16; ++s) {
            const int ks = (s + rot) & 15;
            const int aoff = (ks*64 + lane)*8;
            const short8 ahi = *(const short8*)&sH[aoff];
            const short8 alo = *(const short8*)&sL[aoff];
            const short8 wf  = *(const short8*)&W3P[((size_t)(jt*16 + ks)*64 + lane)*8];
            oac = __builtin_amdgcn_mfma_f32_16x16x32_bf16(ahi, wf, oac, 0, 0, 0);
            oac = __builtin_amdgcn_mfma_f32_16x16x32_bf16(alo, wf, oac, 0, 0, 0);
        }
        if (j < Dn) {
            #pragma unroll
            for (int q = 0; q < 4; ++q)
                out[(size_t)(r0 + kg*4 + q)*Dn + j] = oac[q];
        }
    }
}

extern "C" void kernel_launch(void* const* d_in, const int* in_sizes, int n_in,
                              void* d_out, int out_size, void* d_ws, size_t ws_size,
                              hipStream_t stream)
{
    const float* xs = (const float*)d_in[0];
    const float* t  = (const float*)d_in[1];
    const float* W1 = (const float*)d_in[2];
    const float* b1 = (const float*)d_in[3];
    const float* W2 = (const float*)d_in[4];
    const float* b2 = (const float*)d_in[5];
    const float* W3 = (const float*)d_in[6];
    const float* b3 = (const float*)d_in[7];
    float* out = (float*)d_out;

    char* ws = (char*)d_ws;
    unsigned short* WQ   = (unsigned short*)(ws);                 // 1 MB interleaved W2|Cm
    unsigned short* W3P  = (unsigned short*)(ws + 1048576);       // 80 KB
    unsigned int*  doneCtr = (unsigned int*)(ws + 2097152);       // 64 B flag line

    hipMemsetAsync(doneCtr, 0, 64, stream);
    k_single<<<256, 1024, 0, stream>>>(xs, t, W1, b1, W2, b2, W3, b3,
                                       WQ, W3P, doneCtr, out);
}

// Round 4
// 124.393 us; speedup vs baseline: 1.3268x; 1.0921x over previous
//
#include <hip/hip_runtime.h>

#define Bn 4096
#define Dn 66
#define Hn 512

typedef __attribute__((ext_vector_type(8))) short short8;
typedef __attribute__((ext_vector_type(4))) float f32x4;

__device__ __forceinline__ unsigned short f2bf(float x) {
    union { float f; unsigned u; } v; v.f = x;
    unsigned r = v.u + 0x7fffu + ((v.u >> 16) & 1u);   // RNE
    return (unsigned short)(r >> 16);
}
__device__ __forceinline__ float bf2f(unsigned short h) {
    union { float f; unsigned u; } v; v.u = ((unsigned)h) << 16; return v.f;
}

// Layouts (unchanged from verified kernels):
//   A-frag tile ks: lane l holds A[l&15][ks*32 + (l>>4)*8 + j]  at (ks*64 + l)*8 + j
//   WQ interleaved B-frag tile (ct, ks): W2-frag at ((ct*16+ks)*64+l)*16 + 0..7,
//       Cm-frag at +8..15
//   W3P B-frag tile (jt, ks): ((jt*16+ks)*64 + l)*8 + j

// ============ k_single: ONE regular dispatch, grid 256 x 1024 ============
// Sync protocol v2 (this round's only change):
//   producer waves signal IMMEDIATELY after their own pack stores
//   (threadfence release + RELAXED per-wave add; 512 WQ waves + 80 W3P = 592);
//   consumer tid0 RELAXED-polls (no per-poll cache invalidation), one
//   threadfence after exit, __syncthreads. Everything else byte-identical.
__global__ __launch_bounds__(1024, 4) void k_single(
    const float* __restrict__ xs, const float* __restrict__ tt,
    const float* __restrict__ W1, const float* __restrict__ b1,
    const float* __restrict__ W2, const float* __restrict__ b2,
    const float* __restrict__ W3, const float* __restrict__ b3,
    unsigned short* __restrict__ WQ, unsigned short* __restrict__ W3P,
    unsigned int* __restrict__ doneCtr,
    float* __restrict__ out)
{
    __shared__ float sX[67*16];                          // x~^T staging [i][r]
    __shared__ __align__(16) unsigned short sA[8192];    // h1 hi A-frags (16 KB)
    __shared__ __align__(16) unsigned short sS[8192];    // s1 A-frags   (16 KB)
    __shared__ __align__(16) unsigned short sH[8192];    // h2 hi (16 KB)
    __shared__ __align__(16) unsigned short sL[8192];    // h2 lo (16 KB)
    __shared__ float sRed[16*16];

    const int tid = threadIdx.x, lane = tid & 63, wv = tid >> 6;   // wv 0..15
    const int rt = blockIdx.x, r0 = rt*16;
    const int n = lane & 15, kg = lane >> 4;
    const int rot = (rt >> 3) & 15;

    // ---- stage x~^T (row 66 = t) into sX[i*16 + r] ----
    for (int idx = tid; idx < 67*16; idx += 1024) {
        const int i = idx >> 4, r = idx & 15;
        sX[idx] = (i < Dn) ? xs[(size_t)(r0+r)*Dn + i] : tt[r0+r];
    }
    __syncthreads();

    // ---- pack tasks (weight-only); each pack wave signals when ITS stores done ----
    if (wv < 2) {
        const int tix = wv*256 + rt;               // 0..511 = (ct 0..31, ks 0..15)
        const int ct = tix >> 4, ks = tix & 15;
        const int c = ct*16 + n;
        const int abase = ks*32 + kg*8;
        float w2v[8], m[8];
        #pragma unroll
        for (int j = 0; j < 8; ++j) {
            w2v[j] = W2[(size_t)(abase + j)*Hn + c];
            m[j] = 0.f;
        }
        const float* w3row = &W3[(size_t)c * Dn];
        #pragma unroll 2
        for (int i = 0; i < Dn; ++i) {
            const float w3 = w3row[i];
            const float4 w1a = *(const float4*)&W1[(size_t)i*Hn + abase];
            const float4 w1b = *(const float4*)&W1[(size_t)i*Hn + abase + 4];
            m[0] = fmaf(w3, w1a.x, m[0]); m[1] = fmaf(w3, w1a.y, m[1]);
            m[2] = fmaf(w3, w1a.z, m[2]); m[3] = fmaf(w3, w1a.w, m[3]);
            m[4] = fmaf(w3, w1b.x, m[4]); m[5] = fmaf(w3, w1b.y, m[5]);
            m[6] = fmaf(w3, w1b.z, m[6]); m[7] = fmaf(w3, w1b.w, m[7]);
        }
        short8 pw, pc;
        #pragma unroll
        for (int j = 0; j < 8; ++j) {
            pw[j] = (short)f2bf(w2v[j]);
            pc[j] = (short)f2bf(w2v[j] * m[j]);
        }
        const size_t off = ((size_t)tix*64 + lane)*16;
        *(short8*)&WQ[off]     = pw;
        *(short8*)&WQ[off + 8] = pc;
        __threadfence();                            // release: wave's stores -> device
        if (lane == 0)
            __hip_atomic_fetch_add(doneCtr, 1u, __ATOMIC_RELAXED, __HIP_MEMORY_SCOPE_AGENT);
    } else if (wv == 2 && rt < 80) {
        const int tix = rt;                        // 0..79 = (jt 0..4, ks 0..15)
        const int ks = tix & 15;
        const int j_out = (tix >> 4)*16 + n;
        const int abase = ks*32 + kg*8;
        short8 p;
        #pragma unroll
        for (int j = 0; j < 8; ++j)
            p[j] = (j_out < Dn) ? (short)f2bf(W3[(size_t)(abase + j)*Dn + j_out]) : (short)0;
        *(short8*)&W3P[((size_t)tix*64 + lane)*8] = p;
        __threadfence();
        if (lane == 0)
            __hip_atomic_fetch_add(doneCtr, 1u, __ATOMIC_RELAXED, __HIP_MEMORY_SCOPE_AGENT);
    }

    // ---- phase A: z1 = [x,t]@W1 + b1 (fp32 VALU); wave wv owns ks-tile wv ----
    {
        const int rg = lane & 7, cg = lane >> 3;
        const int ks = wv;
        const int c0 = ks*32 + cg*4;
        const int irot = (rt >> 3) & 31;
        float z[2][4];
        {
            const float4 b4 = *(const float4*)&b1[c0];
            z[0][0]=b4.x; z[0][1]=b4.y; z[0][2]=b4.z; z[0][3]=b4.w;
            z[1][0]=b4.x; z[1][1]=b4.y; z[1][2]=b4.z; z[1][3]=b4.w;
        }
        #pragma unroll 2
        for (int s = 0; s < 67; ++s) {
            int i = s + irot; if (i >= 67) i -= 67;
            const float2 xf = *(const float2*)&sX[i*16 + 2*rg];
            const float4 wA = *(const float4*)&W1[(size_t)i*Hn + c0];
            const float ww[4] = {wA.x, wA.y, wA.z, wA.w};
            #pragma unroll
            for (int j = 0; j < 4; ++j) {
                z[0][j] = fmaf(xf.x, ww[j], z[0][j]);
                z[1][j] = fmaf(xf.y, ww[j], z[1][j]);
            }
        }
        const int kgrp = cg >> 1, joff = (cg & 1)*4;
        #pragma unroll
        for (int rr = 0; rr < 2; ++rr) {
            const int r = 2*rg + rr;
            ushort4 phi, ps;
            unsigned short* PH = (unsigned short*)&phi;
            unsigned short* PS = (unsigned short*)&ps;
            #pragma unroll
            for (int j = 0; j < 4; ++j) {
                const float zv = z[rr][j];
                const float sg = 1.f / (1.f + __expf(-zv));
                PH[j] = f2bf(zv * sg);
                PS[j] = f2bf(sg * (1.f + zv * (1.f - sg)));
            }
            const int off = (ks*64 + r + 16*kgrp)*8 + joff;
            *(ushort4*)&sA[off] = phi;
            *(ushort4*)&sS[off] = ps;
        }
    }

    // ---- wait: all 592 pack waves signaled. Relaxed poll (no inv), one fence. ----
    if (tid == 0) {
        while (__hip_atomic_load(doneCtr, __ATOMIC_RELAXED, __HIP_MEMORY_SCOPE_AGENT) < 592u)
            __builtin_amdgcn_s_sleep(8);
        __threadfence();                            // acquire: invalidate once
    }
    __syncthreads();                                // also covers LDS A-frags

    // ---- phase B: z2 = h1hi@W2 + b2, v = s1'@Cmat; A/S from LDS, WQ prefetched ----
    const int ctb = wv*2;
    f32x4 zac[2], vac[2];
    #pragma unroll
    for (int ti = 0; ti < 2; ++ti) {
        const float bz = b2[(ctb + ti)*16 + n];
        zac[ti] = (f32x4){bz, bz, bz, bz};
        vac[ti] = (f32x4){0.f, 0.f, 0.f, 0.f};
    }
    short8 wbuf[2][2], qbuf[2][2], abuf[2], sbuf[2];
    {
        const int ks0 = rot;
        abuf[0] = *(const short8*)&sA[(ks0*64 + lane)*8];
        sbuf[0] = *(const short8*)&sS[(ks0*64 + lane)*8];
        #pragma unroll
        for (int ti = 0; ti < 2; ++ti) {
            const size_t wo = ((size_t)((ctb + ti)*16 + ks0)*64 + lane)*16;
            wbuf[0][ti] = *(const short8*)&WQ[wo];
            qbuf[0][ti] = *(const short8*)&WQ[wo + 8];
        }
    }
    #pragma unroll
    for (int s = 0; s < 16; ++s) {
        const int cur = s & 1, nxt = cur ^ 1;
        if (s < 15) {
            const int ksn = (s + 1 + rot) & 15;
            abuf[nxt] = *(const short8*)&sA[(ksn*64 + lane)*8];
            sbuf[nxt] = *(const short8*)&sS[(ksn*64 + lane)*8];
            #pragma unroll
            for (int ti = 0; ti < 2; ++ti) {
                const size_t wo = ((size_t)((ctb + ti)*16 + ksn)*64 + lane)*16;
                wbuf[nxt][ti] = *(const short8*)&WQ[wo];
                qbuf[nxt][ti] = *(const short8*)&WQ[wo + 8];
            }
        }
        #pragma unroll
        for (int ti = 0; ti < 2; ++ti) {
            zac[ti] = __builtin_amdgcn_mfma_f32_16x16x32_bf16(abuf[cur], wbuf[cur][ti], zac[ti], 0, 0, 0);
            vac[ti] = __builtin_amdgcn_mfma_f32_16x16x32_bf16(sbuf[cur], qbuf[cur][ti], vac[ti], 0, 0, 0);
        }
    }

    // ---- epilogue: h2 hi/lo -> LDS; dp partial reduce ----
    float dp[4] = {0.f, 0.f, 0.f, 0.f};
    #pragma unroll
    for (int ti = 0; ti < 2; ++ti) {
        const int c = (ctb + ti)*16 + n;
        const int ks2 = c >> 5, kg2 = (c >> 3) & 3, j2 = c & 7;
        #pragma unroll
        for (int q = 0; q < 4; ++q) {
            const float z2 = zac[ti][q];
            const float sg = 1.f / (1.f + __expf(-z2));
            const float h2 = z2 * sg;
            dp[q] = fmaf(sg * (1.f + z2 * (1.f - sg)), vac[ti][q], dp[q]);
            const unsigned short hh = f2bf(h2);
            const int o = (ks2*64 + (kg*4 + q) + 16*kg2)*8 + j2;
            sH[o] = hh;
            sL[o] = f2bf(h2 - bf2f(hh));
        }
    }
    #pragma unroll
    for (int q = 0; q < 4; ++q) {
        float v = dp[q];
        v += __shfl_xor(v, 1, 64);
        v += __shfl_xor(v, 2, 64);
        v += __shfl_xor(v, 4, 64);
        v += __shfl_xor(v, 8, 64);
        if (n == 0) sRed[wv*16 + kg*4 + q] = v;
    }
    __syncthreads();

    // ---- divergence finalize ----
    if (tid < 16) {
        float s = 0.f;
        #pragma unroll
        for (int q = 0; q < 16; ++q) s += sRed[q*16 + tid];
        out[(size_t)Bn*Dn + r0 + tid] = -s;
    }

    // ---- phase C: out = h2 @ W3 + b3 (waves 0..4); rotated ks ----
    if (wv < 5) {
        const int jt = wv;
        const int j = jt*16 + n;
        const float bj = (j < Dn) ? b3[j] : 0.f;
        f32x4 oac = (f32x4){bj, bj, bj, bj};
        #pragma unroll 4
        for (int s = 0; s < 16; ++s) {
            const int ks = (s + rot) & 15;
            const int aoff = (ks*64 + lane)*8;
            const short8 ahi = *(const short8*)&sH[aoff];
            const short8 alo = *(const short8*)&sL[aoff];
            const short8 wf  = *(const short8*)&W3P[((size_t)(jt*16 + ks)*64 + lane)*8];
            oac = __builtin_amdgcn_mfma_f32_16x16x32_bf16(ahi, wf, oac, 0, 0, 0);
            oac = __builtin_amdgcn_mfma_f32_16x16x32_bf16(alo, wf, oac, 0, 0, 0);
        }
        if (j < Dn) {
            #pragma unroll
            for (int q = 0; q < 4; ++q)
                out[(size_t)(r0 + kg*4 + q)*Dn + j] = oac[q];
        }
    }
}

extern "C" void kernel_launch(void* const* d_in, const int* in_sizes, int n_in,
                              void* d_out, int out_size, void* d_ws, size_t ws_size,
                              hipStream_t stream)
{
    const float* xs = (const float*)d_in[0];
    const float* t  = (const float*)d_in[1];
    const float* W1 = (const float*)d_in[2];
    const float* b1 = (const float*)d_in[3];
    const float* W2 = (const float*)d_in[4];
    const float* b2 = (const float*)d_in[5];
    const float* W3 = (const float*)d_in[6];
    const float* b3 = (const float*)d_in[7];
    float* out = (float*)d_out;

    char* ws = (char*)d_ws;
    unsigned short* WQ   = (unsigned short*)(ws);                 // 1 MB interleaved W2|Cm
    unsigned short* W3P  = (unsigned short*)(ws + 1048576);       // 80 KB
    unsigned int*  doneCtr = (unsigned int*)(ws + 2097152);       // 64 B flag line

    hipMemsetAsync(doneCtr, 0, 64, stream);
    k_single<<<256, 1024, 0, stream>>>(xs, t, W1, b1, W2, b2, W3, b3,
                                       WQ, W3P, doneCtr, out);
}